// Round 4
// baseline (1782.198 us; speedup 1.0000x reference)
//
#include <hip/hip_runtime.h>
#include <math.h>

// Problem constants (PMS_1): B=4, C=64, H=W=128
constexpr int B = 4, C = 64, H = 128, W = 128;
constexpr int HW = H * W;
constexpr size_t PLANE = (size_t)HW;          // 16384
constexpr size_t CHW   = (size_t)C * HW;      // 1,048,576
constexpr size_t TOT   = (size_t)B * CHW;     // 4,194,304
constexpr float SCALE  = 1.0f / 24.0f;        // 1/sqrt(C*9)

typedef _Float16 half8 __attribute__((ext_vector_type(8)));
typedef float floatx4 __attribute__((ext_vector_type(4)));

// Weight arena (fp16). Per conv: KK steps x 4096 halfs.
// Within a step: half idx l = (h*4+mt)*512 + q*128 + l15*8 + j
//   -> holds W[oc=mt*16+l15][ic=h*32+q*8+j][kh][kw] * scale, kk=kh*K+kw.
constexpr size_t WT_RES = 0;         // 18 x 36864
constexpr size_t WT_M1  = 663552;    // 10 x 4096
constexpr size_t WT_M3  = 704512;    // 10 x 36864
constexpr size_t WT_M5  = 1073152;   // 10 x 102400
constexpr size_t WT_TOT = 2097152;   // halfs = 4 MiB

__global__ __launch_bounds__(256) void wt_kernel(
    const float* __restrict__ rw, const float* __restrict__ mw1,
    const float* __restrict__ mw3, const float* __restrict__ mw5,
    _Float16* __restrict__ wt)
{
    int e = blockIdx.x * 256 + threadIdx.x;
    const float* src; int K; float scale; int l;
    if (e < (int)WT_M1) {
        int conv = e / 36864; l = e - conv * 36864;
        src = rw + (size_t)conv * 36864; K = 3; scale = SCALE;
    } else if (e < (int)WT_M3) {
        int e2 = e - (int)WT_M1; int conv = e2 / 4096; l = e2 - conv * 4096;
        src = mw1 + (size_t)conv * 4096; K = 1; scale = 1.f;
    } else if (e < (int)WT_M5) {
        int e2 = e - (int)WT_M3; int conv = e2 / 36864; l = e2 - conv * 36864;
        src = mw3 + (size_t)conv * 36864; K = 3; scale = 1.f;
    } else {
        int e2 = e - (int)WT_M5; int conv = e2 / 102400; l = e2 - conv * 102400;
        src = mw5 + (size_t)conv * 102400; K = 5; scale = 1.f;
    }
    int j   = l & 7;
    int l15 = (l >> 3) & 15;
    int q   = (l >> 7) & 3;
    int mt  = (l >> 9) & 3;
    int h   = (l >> 11) & 1;
    int kk  = l >> 12;
    int oc = mt * 16 + l15, ic = h * 32 + q * 8 + j;
    int kh = kk / K, kw = kk - kh * K;
    wt[e] = (_Float16)(src[((oc * C + ic) * K + kh) * K + kw] * scale);
}

// ---------------------------------------------------------------------------
// Implicit-GEMM conv, fp16 MFMA 16x16x32, A and B both from LDS.
// Block: 128 thr (2 waves), tile 8x16 px x 64 oc. Wave: 64 oc x 64 px
// (rows 4wv..4wv+3), acc[4][4]. Grid 512 -> 2 blocks/CU.
// s_b: [h][px][16 dwords] (stride 16 dw) -> B b128 reads are contiguous
//      1KB/wave, lane-distinct 16B = conflict-free.
// s_a: per-(kh,kw) 8KB A chunk, double-buffered, prefetched during compute.
//      A b128 reads contiguous 1KB/wave = conflict-free.
// ---------------------------------------------------------------------------
template <int K, int ACT>
__global__ __launch_bounds__(128, 1) void mconv_kernel(
    const float* __restrict__ in, const _Float16* __restrict__ wt,
    const float* __restrict__ bias, const float* __restrict__ cond,
    const float* __restrict__ res, float* __restrict__ out)
{
    constexpr int P = K / 2, KK = K * K;
    constexpr int CO  = (K == 1) ? 0 : 2;     // staged col 0 == x0 - CO
    constexpr int IHs = 8 + K - 1;
    constexpr int IWs = (K == 1) ? 16 : 20;
    constexpr int NPX = IHs * IWs;
    constexpr int HP  = NPX * 16;             // dwords per h-plane
    constexpr int XP  = IWs / 2;
    constexpr int NP2 = IHs * XP;             // float2 positions
    __shared__ __align__(16) unsigned int s_b[NPX * 32];
    __shared__ __align__(16) unsigned int s_a[2][2048];

    const int tid = threadIdx.x;
    const int bx = blockIdx.x, b = blockIdx.y;
    const int y0 = (bx >> 3) * 8, x0 = (bx & 7) * 16;

    // ---- stage input tile (halo, zero-pad, cond-scale, fp16)
    for (int idx = tid; idx < NP2 * 32; idx += 128) {
        int icp = idx & 31;                   // ic-pair (dword) index
        int pp  = idx >> 5;
        int xp = pp % XP, r = pp / XP;
        int gy = y0 + r - P, gx = x0 + 2 * xp - CO;
        float2 va = make_float2(0.f, 0.f), vb = make_float2(0.f, 0.f);
        if (gy >= 0 && gy < H && gx >= 0 && gx < W) {
            size_t base = ((size_t)(b * C + 2 * icp) * H + gy) * W + gx;
            va = *(const float2*)&in[base];
            vb = *(const float2*)&in[base + PLANE];
        }
        if (cond) {
            float c0 = cond[b * C + 2 * icp], c1 = cond[b * C + 2 * icp + 1];
            va.x *= c0; va.y *= c0; vb.x *= c1; vb.y *= c1;
        }
        int h = icp >> 4, ii = icp & 15;
        int px = r * IWs + 2 * xp;
        _Float16 lo0 = (_Float16)va.x, hi0 = (_Float16)vb.x;
        _Float16 lo1 = (_Float16)va.y, hi1 = (_Float16)vb.y;
        unsigned int d0 = ((unsigned int)__builtin_bit_cast(unsigned short, hi0) << 16)
                        | __builtin_bit_cast(unsigned short, lo0);
        unsigned int d1 = ((unsigned int)__builtin_bit_cast(unsigned short, hi1) << 16)
                        | __builtin_bit_cast(unsigned short, lo1);
        s_b[h * HP + px * 16 + ii]       = d0;
        s_b[h * HP + (px + 1) * 16 + ii] = d1;
    }
    // ---- stage A step 0 (8 KB, coalesced, conflict-free stores)
    {
        const uint4* src = (const uint4*)wt;
        uint4* dst = (uint4*)s_a[0];
#pragma unroll
        for (int i = 0; i < 4; ++i) dst[i * 128 + tid] = src[i * 128 + tid];
    }
    __syncthreads();

    const int lane = tid & 63, wv = tid >> 6;
    const int l15 = lane & 15, q = lane >> 4;

    floatx4 acc[4][4] = {};
    uint4 pre[4];

    for (int step = 0; step < KK; ++step) {
        const int buf = step & 1;
        if (step + 1 < KK) {
            const uint4* src = (const uint4*)(wt + (size_t)(step + 1) * 4096);
#pragma unroll
            for (int i = 0; i < 4; ++i) pre[i] = src[i * 128 + tid];
        }
        const int kh = step / K, kw = step - kh * K;
        const unsigned int* sa = s_a[buf];
#pragma unroll
        for (int h = 0; h < 2; ++h) {
            half8 af[4], bf[4];
#pragma unroll
            for (int mt = 0; mt < 4; ++mt) {
                const uint4 u = *(const uint4*)&sa[((h * 4 + mt) * 64 + q * 16 + l15) * 4];
                af[mt] = __builtin_bit_cast(half8, u);
            }
#pragma unroll
            for (int ng = 0; ng < 4; ++ng) {
                int row = 4 * wv + ng + kh;
                int col = l15 + kw - P + CO;
                const uint4 u = *(const uint4*)&s_b[h * HP + (row * IWs + col) * 16 + q * 4];
                bf[ng] = __builtin_bit_cast(half8, u);
            }
#pragma unroll
            for (int ng = 0; ng < 4; ++ng) {
#pragma unroll
                for (int mt = 0; mt < 4; ++mt)
                    acc[mt][ng] = __builtin_amdgcn_mfma_f32_16x16x32_f16(
                        af[mt], bf[ng], acc[mt][ng], 0, 0, 0);
            }
        }
        if (step + 1 < KK) {
            uint4* dst = (uint4*)s_a[buf ^ 1];
#pragma unroll
            for (int i = 0; i < 4; ++i) dst[i * 128 + tid] = pre[i];
        }
        __syncthreads();
    }

    // ---- epilogue: D[oc = mt*16 + q*4 + r][px = l15], rows y0 + 4*wv + ng
#pragma unroll
    for (int mt = 0; mt < 4; ++mt) {
#pragma unroll
        for (int r = 0; r < 4; ++r) {
            const int oc = mt * 16 + q * 4 + r;
            const float bv = bias ? bias[oc] : 0.f;
#pragma unroll
            for (int ng = 0; ng < 4; ++ng) {
                const int y = y0 + 4 * wv + ng, x = x0 + l15;
                const size_t o = ((size_t)(b * C + oc) * H + y) * W + x;
                float v = acc[mt][ng][r] + bv;
                if (ACT == 1) v = fmaxf(v, 0.f);
                if (ACT == 2) v = v > 0.f ? v : 0.01f * v;
                if (res) v += res[o];
                out[o] = v;
            }
        }
    }
}

// ---------------------------------------------------------------------------
__global__ __launch_bounds__(256) void pool_kernel(
    const float* __restrict__ o, float* __restrict__ mx, float* __restrict__ av)
{
    const int bc = blockIdx.x;
    const float* p = o + (size_t)bc * PLANE;
    const int tid = threadIdx.x;
    float m = -INFINITY, s = 0.f;
    for (int i = tid; i < HW; i += 256) {
        float v = p[i];
        m = fmaxf(m, v);
        s += v;
    }
#pragma unroll
    for (int off = 32; off > 0; off >>= 1) {
        m = fmaxf(m, __shfl_down(m, off));
        s += __shfl_down(s, off);
    }
    __shared__ float sm[4], ss[4];
    if ((tid & 63) == 0) { sm[tid >> 6] = m; ss[tid >> 6] = s; }
    __syncthreads();
    if (tid == 0) {
        m = fmaxf(fmaxf(sm[0], sm[1]), fmaxf(sm[2], sm[3]));
        s = ss[0] + ss[1] + ss[2] + ss[3];
        mx[bc] = m;
        av[bc] = s * (1.f / HW);
    }
}

__global__ __launch_bounds__(256) void cg_kernel(
    const float* __restrict__ mx, const float* __restrict__ av,
    const float* __restrict__ caw1, const float* __restrict__ caw2,
    const float* __restrict__ fcw, const float* __restrict__ fcb,
    float* __restrict__ Cg)
{
    __shared__ float hid[2][4][4];
    const int t = threadIdx.x;
    if (t < 32) {
        int which = t >> 4, b = (t >> 2) & 3, h = t & 3;
        const float* src = which ? av : mx;
        float s = 0.f;
        for (int i = 0; i < C; ++i) s += caw1[h * C + i] * src[b * C + i];
        hid[which][b][h] = fmaxf(s, 0.f);
    }
    __syncthreads();
    int b = t >> 6, c = t & 63;
    float s = 0.f;
#pragma unroll
    for (int h = 0; h < 4; ++h)
        s += caw2[c * 4 + h] * (hid[0][b][h] + hid[1][b][h]);
    float xll = 1.f / (1.f + expf(-s));
    Cg[t] = fcw[1] * (fcw[0] * xll + fcb[0]) + fcb[1];
}

__global__ __launch_bounds__(256) void cgmul_kernel(
    const float* __restrict__ acc, const float* __restrict__ Cg, float* __restrict__ o)
{
    size_t i = (size_t)blockIdx.x * 256 + threadIdx.x;
    size_t e = i * 4;
    int bc = (int)(e / PLANE);
    float g = Cg[bc];
    float4 v = ((const float4*)acc)[i];
    v.x *= g; v.y *= g; v.z *= g; v.w *= g;
    ((float4*)o)[i] = v;
}

__global__ __launch_bounds__(256) void final_kernel(
    const float* __restrict__ o, const float* __restrict__ mapp,
    const float* __restrict__ x, float* __restrict__ out)
{
    size_t i = (size_t)blockIdx.x * 256 + threadIdx.x;
    size_t e = i * 4;
    size_t b = e / CHW;
    size_t pos = e % PLANE;
    float4 ov = ((const float4*)o)[i];
    float4 xv = ((const float4*)x)[i];
    float4 mv = ((const float4*)(mapp + b * PLANE))[pos >> 2];
    float4 r;
    r.x = fmaf(ov.x, mv.x, xv.x);
    r.y = fmaf(ov.y, mv.y, xv.y);
    r.z = fmaf(ov.z, mv.z, xv.z);
    r.w = fmaf(ov.w, mv.w, xv.w);
    ((float4*)out)[i] = r;
}

extern "C" void kernel_launch(void* const* d_in, const int* in_sizes, int n_in,
                              void* d_out, int out_size, void* d_ws, size_t ws_size,
                              hipStream_t stream)
{
    const float* x    = (const float*)d_in[0];
    const float* cf1  = (const float*)d_in[1];
    const float* cf2  = (const float*)d_in[2];
    const float* mapp = (const float*)d_in[3];
    const float* rw   = (const float*)d_in[4];
    const float* rb   = (const float*)d_in[5];
    const float* mw1  = (const float*)d_in[6];
    const float* mb1  = (const float*)d_in[7];
    const float* mw3  = (const float*)d_in[8];
    const float* mb3  = (const float*)d_in[9];
    const float* mw5  = (const float*)d_in[10];
    const float* mb5  = (const float*)d_in[11];
    const float* caw1 = (const float*)d_in[12];
    const float* caw2 = (const float*)d_in[13];
    const float* fcw  = (const float*)d_in[14];
    const float* fcb  = (const float*)d_in[15];
    float* out = (float*)d_out;

    _Float16* wta = (_Float16*)d_ws;
    float* fbase  = (float*)((char*)d_ws + WT_TOT * sizeof(_Float16));
    float* buf_o   = fbase;
    float* buf_t   = fbase + TOT;
    float* buf_acc = fbase + 2 * TOT;
    float* st      = fbase + 3 * TOT;
    float* mx = st, *av = st + 256, *Cg = st + 512;

    wt_kernel<<<dim3((unsigned)(WT_TOT / 256)), 256, 0, stream>>>(rw, mw1, mw3, mw5, wta);

    const dim3 cgrid(128, B);   // (H/8)*(W/16)=128 tiles, 128 threads
    const dim3 egrid((unsigned)(TOT / 1024));

    int mfe_j = 0;
    for (int i = 0; i < 9; ++i) {
        const float* condb = (i < 5) ? (cf1 + (size_t)i * 2 * B * C)
                                     : (cf2 + (size_t)(i - 5) * 2 * B * C);
        const float* in0 = (i == 0) ? x : buf_o;
        const _Float16* rw0 = wta + WT_RES + (size_t)(i * 2 + 0) * 36864;
        const _Float16* rw1 = wta + WT_RES + (size_t)(i * 2 + 1) * 36864;
        const float* rb0 = rb + (i * 2 + 0) * C;
        const float* rb1 = rb + (i * 2 + 1) * C;
        mconv_kernel<3, 1><<<cgrid, 128, 0, stream>>>(in0, rw0, rb0, condb, nullptr, buf_t);
        mconv_kernel<3, 0><<<cgrid, 128, 0, stream>>>(buf_t, rw1, rb1, condb + B * C, in0, buf_o);

        if (i == 1 || i == 3 || i == 5 || i == 7 || i == 8) {
            int j = mfe_j++;
            const _Float16* w10 = wta + WT_M1 + (size_t)(j * 2 + 0) * 4096;
            const _Float16* w11 = wta + WT_M1 + (size_t)(j * 2 + 1) * 4096;
            const _Float16* w30 = wta + WT_M3 + (size_t)(j * 2 + 0) * 36864;
            const _Float16* w31 = wta + WT_M3 + (size_t)(j * 2 + 1) * 36864;
            const _Float16* w50 = wta + WT_M5 + (size_t)(j * 2 + 0) * 102400;
            const _Float16* w51 = wta + WT_M5 + (size_t)(j * 2 + 1) * 102400;
            const float* b10 = mb1 + (j * 2 + 0) * C, *b11 = mb1 + (j * 2 + 1) * C;
            const float* b30 = mb3 + (j * 2 + 0) * C, *b31 = mb3 + (j * 2 + 1) * C;
            const float* b50 = mb5 + (j * 2 + 0) * C, *b51 = mb5 + (j * 2 + 1) * C;

            pool_kernel<<<dim3(B * C), 256, 0, stream>>>(buf_o, mx, av);
            cg_kernel<<<1, 256, 0, stream>>>(mx, av, caw1 + j * 4 * C, caw2 + j * C * 4,
                                             fcw + j * 2, fcb + j * 2, Cg);

            mconv_kernel<1, 2><<<cgrid, 128, 0, stream>>>(buf_o, w10, b10, nullptr, nullptr, buf_t);
            mconv_kernel<1, 0><<<cgrid, 128, 0, stream>>>(buf_t, w11, b11, nullptr, nullptr, buf_acc);
            mconv_kernel<3, 2><<<cgrid, 128, 0, stream>>>(buf_o, w30, b30, nullptr, nullptr, buf_t);
            mconv_kernel<3, 0><<<cgrid, 128, 0, stream>>>(buf_t, w31, b31, nullptr, buf_acc, buf_acc);
            mconv_kernel<5, 2><<<cgrid, 128, 0, stream>>>(buf_o, w50, b50, nullptr, nullptr, buf_t);
            mconv_kernel<5, 0><<<cgrid, 128, 0, stream>>>(buf_t, w51, b51, nullptr, buf_acc, buf_acc);

            cgmul_kernel<<<egrid, 256, 0, stream>>>(buf_acc, Cg, buf_o);
        }
    }
    final_kernel<<<egrid, 256, 0, stream>>>(buf_o, mapp, x, out);
}

// Round 5
// 868.299 us; speedup vs baseline: 2.0525x; 2.0525x over previous
//
#include <hip/hip_runtime.h>
#include <math.h>

// Problem constants (PMS_1): B=4, C=64, H=W=128
constexpr int B = 4, C = 64, H = 128, W = 128;
constexpr int HW = H * W;
constexpr size_t PLANE = (size_t)HW;          // 16384
constexpr size_t TOT   = (size_t)B * C * HW;  // 4,194,304 elements
constexpr float SCALE  = 1.0f / 24.0f;        // 1/sqrt(C*9)

typedef _Float16 half8 __attribute__((ext_vector_type(8)));
typedef _Float16 half4v __attribute__((ext_vector_type(4)));
typedef float floatx4 __attribute__((ext_vector_type(4)));

// fp16 weight arena. Per conv-step (one (kh,kw)): 4096 halfs,
// half idx l = (h*4+mt)*512 + q*128 + l15*8 + j
//   -> W[oc=mt*16+l15][ic=h*32+q*8+j] (* scale * cond for res convs).
// Res convs have per-sample copies (cond folded): [conv 0..17][b 0..3].
constexpr size_t A_RES = 0;                   // 18*4 x 36864
constexpr size_t A_M1  = 2654208;             // 10 x 4096
constexpr size_t A_M3  = 2695168;             // 10 x 36864
constexpr size_t A_M5  = 3063808;             // 10 x 102400
constexpr size_t A_TOT = 4087808;             // halfs (= 15968 * 256)

__global__ __launch_bounds__(256) void wt_kernel(
    const float* __restrict__ rw, const float* __restrict__ mw1,
    const float* __restrict__ mw3, const float* __restrict__ mw5,
    const float* __restrict__ cf1, const float* __restrict__ cf2,
    _Float16* __restrict__ wt)
{
    size_t e = (size_t)blockIdx.x * 256 + threadIdx.x;
    const float* src; int K; float scale; int l;
    if (e < A_M1) {
        int cb = (int)(e / 36864); l = (int)(e - (size_t)cb * 36864);
        int conv = cb >> 2, b = cb & 3;
        src = rw + (size_t)conv * 36864; K = 3;
        // cond for this conv layer & sample, per input channel (applied below)
        int icw = l & 7, l15 = (l >> 3) & 15, q = (l >> 7) & 3;
        int mt = (l >> 9) & 3, h = (l >> 11) & 1, kk = l >> 12;
        int oc = mt * 16 + l15, ic = h * 32 + q * 8 + icw;
        int kh = kk / 3, kw = kk - kh * 3;
        float cond = (conv < 10) ? cf1[(size_t)(conv * 4 + b) * 64 + ic]
                                 : cf2[(size_t)((conv - 10) * 4 + b) * 64 + ic];
        wt[e] = (_Float16)(src[((oc * C + ic) * 3 + kh) * 3 + kw] * SCALE * cond);
        return;
    } else if (e < A_M3) {
        int e2 = (int)(e - A_M1); int conv = e2 / 4096; l = e2 - conv * 4096;
        src = mw1 + (size_t)conv * 4096; K = 1; scale = 1.f;
    } else if (e < A_M5) {
        int e2 = (int)(e - A_M3); int conv = e2 / 36864; l = e2 - conv * 36864;
        src = mw3 + (size_t)conv * 36864; K = 3; scale = 1.f;
    } else {
        int e2 = (int)(e - A_M5); int conv = e2 / 102400; l = e2 - conv * 102400;
        src = mw5 + (size_t)conv * 102400; K = 5; scale = 1.f;
    }
    int j   = l & 7;
    int l15 = (l >> 3) & 15;
    int q   = (l >> 7) & 3;
    int mt  = (l >> 9) & 3;
    int h   = (l >> 11) & 1;
    int kk  = l >> 12;
    int oc = mt * 16 + l15, ic = h * 32 + q * 8 + j;
    int kh = kk / K, kw = kk - kh * K;
    wt[e] = (_Float16)(src[((oc * C + ic) * K + kh) * K + kw] * scale);
}

// x fp32 NCHW -> fp16 NHWC (channels-last), LDS transpose
__global__ __launch_bounds__(256) void xcvt_kernel(
    const float* __restrict__ x, _Float16* __restrict__ xh)
{
    __shared__ _Float16 s[64 * 72];
    const int b = blockIdx.y;
    const size_t p0 = (size_t)blockIdx.x * 64;
    const int t = threadIdx.x, px = t & 63, cg0 = t >> 6;
#pragma unroll
    for (int k = 0; k < 16; ++k) {
        int c = cg0 * 16 + k;
        s[px * 72 + c] = (_Float16)x[((size_t)(b * 64 + c)) * HW + p0 + px];
    }
    __syncthreads();
#pragma unroll
    for (int k = 0; k < 2; ++k) {
        int idx = k * 256 + t;
        int pxw = idx >> 3, o8 = idx & 7;
        uint4 v = *(const uint4*)&s[pxw * 72 + o8 * 8];
        *(uint4*)&xh[((size_t)b * HW + p0 + pxw) * 64 + o8 * 8] = v;
    }
}

// ---------------------------------------------------------------------------
// Implicit-GEMM conv, fp16 MFMA 16x16x32, channels-last fp16 activations.
// Block: 256 thr (4 waves), tile 8x16 px x 64 oc; wave = 64 oc x 32 px
// (rows 2wv, 2wv+1), acc[4][2]. Grid 512 -> 2 blocks/CU.
// s_b: [o8=h*4+q][px][16B], px stride NPXP ≡ 1 mod 8 -> minimal bank phases.
// s_a: per-step 8KB, double-buffered, register-prefetched.
// Epilogue: v = acc + bias; ACT; v *= Cg (opt); v += res (opt); store fp16.
// ---------------------------------------------------------------------------
template <int K, int ACT>
__global__ __launch_bounds__(256, 2) void mconv_kernel(
    const _Float16* __restrict__ in, const _Float16* __restrict__ wt0,
    const float* __restrict__ bias, int wstride,
    const _Float16* __restrict__ res, const float* __restrict__ cgp,
    _Float16* __restrict__ out)
{
    constexpr int P = K / 2, KK = K * K;
    constexpr int IHs = 8 + K - 1, IWs = 16 + K - 1;
    constexpr int NPX = IHs * IWs;
    constexpr int NPXP = ((NPX + 7) / 8) * 8 + 1;   // ≡ 1 (mod 8)
    __shared__ __align__(16) unsigned int s_b[NPXP * 32];
    __shared__ __align__(16) unsigned int s_a[2][2048];

    const int tid = threadIdx.x;
    const int bx = blockIdx.x, b = blockIdx.y;
    const int y0 = (bx >> 3) * 8, x0 = (bx & 7) * 16;
    const _Float16* wt = wt0 + (size_t)b * wstride;

    // ---- stage B tile: pure copy (cond pre-folded into weights)
    for (int idx = tid; idx < NPX * 8; idx += 256) {
        int px = idx >> 3, o8 = idx & 7;
        int r = px / IWs, cix = px - r * IWs;
        int gy = y0 + r - P, gx = x0 + cix - P;
        uint4 v = {0u, 0u, 0u, 0u};
        if (gy >= 0 && gy < H && gx >= 0 && gx < W)
            v = *(const uint4*)&in[((size_t)b * HW + (size_t)gy * W + gx) * 64 + o8 * 8];
        ((uint4*)s_b)[o8 * NPXP + px] = v;
    }
    // ---- stage A step 0
    {
        const uint4* src = (const uint4*)wt;
        uint4* dst = (uint4*)s_a[0];
#pragma unroll
        for (int i = 0; i < 2; ++i) dst[i * 256 + tid] = src[i * 256 + tid];
    }
    __syncthreads();

    const int lane = tid & 63, wv = tid >> 6;
    const int l15 = lane & 15, q = lane >> 4;

    floatx4 acc[4][2] = {};
    uint4 pre[2];

    for (int step = 0; step < KK; ++step) {
        const int buf = step & 1;
        if (step + 1 < KK) {
            const uint4* src = (const uint4*)(wt + (size_t)(step + 1) * 4096);
#pragma unroll
            for (int i = 0; i < 2; ++i) pre[i] = src[i * 256 + tid];
        }
        const int kh = step / K, kw = step - kh * K;
        const unsigned int* sa = s_a[buf];
#pragma unroll
        for (int h = 0; h < 2; ++h) {
            half8 af[4], bf[2];
#pragma unroll
            for (int mt = 0; mt < 4; ++mt) {
                const uint4 u = ((const uint4*)sa)[(h * 4 + mt) * 64 + q * 16 + l15];
                af[mt] = __builtin_bit_cast(half8, u);
            }
#pragma unroll
            for (int ng = 0; ng < 2; ++ng) {
                int row = 2 * wv + ng + kh;
                int px = row * IWs + l15 + kw;
                const uint4 u = ((const uint4*)s_b)[(h * 4 + q) * NPXP + px];
                bf[ng] = __builtin_bit_cast(half8, u);
            }
#pragma unroll
            for (int ng = 0; ng < 2; ++ng) {
#pragma unroll
                for (int mt = 0; mt < 4; ++mt)
                    acc[mt][ng] = __builtin_amdgcn_mfma_f32_16x16x32_f16(
                        af[mt], bf[ng], acc[mt][ng], 0, 0, 0);
            }
        }
        if (step + 1 < KK) {
            uint4* dst = (uint4*)s_a[buf ^ 1];
#pragma unroll
            for (int i = 0; i < 2; ++i) dst[i * 256 + tid] = pre[i];
            __syncthreads();
        }
    }

    // ---- epilogue: D[oc = mt*16 + q*4 + r][px = l15], rows y0 + 2*wv + ng
#pragma unroll
    for (int mt = 0; mt < 4; ++mt) {
        const int oc0 = mt * 16 + q * 4;
        const float4 bv = *(const float4*)(bias + oc0);
        float4 cg = make_float4(1.f, 1.f, 1.f, 1.f);
        if (cgp) cg = *(const float4*)(cgp + b * 64 + oc0);
#pragma unroll
        for (int ng = 0; ng < 2; ++ng) {
            const int y = y0 + 2 * wv + ng, x = x0 + l15;
            const size_t off = ((size_t)b * HW + (size_t)y * W + x) * 64 + oc0;
            float v[4] = { acc[mt][ng][0] + bv.x, acc[mt][ng][1] + bv.y,
                           acc[mt][ng][2] + bv.z, acc[mt][ng][3] + bv.w };
#pragma unroll
            for (int r = 0; r < 4; ++r) {
                if (ACT == 1) v[r] = fmaxf(v[r], 0.f);
                if (ACT == 2) v[r] = v[r] > 0.f ? v[r] : 0.01f * v[r];
            }
            if (cgp) { v[0] *= cg.x; v[1] *= cg.y; v[2] *= cg.z; v[3] *= cg.w; }
            if (res) {
                half4v rv = *(const half4v*)&res[off];
#pragma unroll
                for (int r = 0; r < 4; ++r) v[r] += (float)rv[r];
            }
            half4v hv = { (_Float16)v[0], (_Float16)v[1], (_Float16)v[2], (_Float16)v[3] };
            *(half4v*)&out[off] = hv;
        }
    }
}

// ---------------------------------------------------------------------------
// Per-(b,c) max & mean over the plane, channels-last input. Grid 32 = (b, o8).
// ---------------------------------------------------------------------------
__global__ __launch_bounds__(256) void pool_kernel(
    const _Float16* __restrict__ o, float* __restrict__ mx, float* __restrict__ av)
{
    const int b = blockIdx.x >> 3, o8 = blockIdx.x & 7;
    const int tid = threadIdx.x;
    float m8[8], s8[8];
#pragma unroll
    for (int j = 0; j < 8; ++j) { m8[j] = -INFINITY; s8[j] = 0.f; }
    for (int px = tid; px < HW; px += 256) {
        uint4 u = *(const uint4*)&o[((size_t)b * HW + px) * 64 + o8 * 8];
        half8 hv = __builtin_bit_cast(half8, u);
#pragma unroll
        for (int j = 0; j < 8; ++j) {
            float f = (float)hv[j];
            m8[j] = fmaxf(m8[j], f);
            s8[j] += f;
        }
    }
#pragma unroll
    for (int off = 32; off > 0; off >>= 1) {
#pragma unroll
        for (int j = 0; j < 8; ++j) {
            m8[j] = fmaxf(m8[j], __shfl_down(m8[j], off));
            s8[j] += __shfl_down(s8[j], off);
        }
    }
    __shared__ float red[4][16];
    const int wv = tid >> 6;
    if ((tid & 63) == 0) {
#pragma unroll
        for (int j = 0; j < 8; ++j) { red[wv][j] = m8[j]; red[wv][8 + j] = s8[j]; }
    }
    __syncthreads();
    if (tid < 8) {
        float m = fmaxf(fmaxf(red[0][tid], red[1][tid]), fmaxf(red[2][tid], red[3][tid]));
        float s = red[0][8 + tid] + red[1][8 + tid] + red[2][8 + tid] + red[3][8 + tid];
        mx[b * 64 + o8 * 8 + tid] = m;
        av[b * 64 + o8 * 8 + tid] = s * (1.f / HW);
    }
}

// Channel attention + FC1 gate -> Cg[b*64+c]. One block.
__global__ __launch_bounds__(256) void cg_kernel(
    const float* __restrict__ mx, const float* __restrict__ av,
    const float* __restrict__ caw1, const float* __restrict__ caw2,
    const float* __restrict__ fcw, const float* __restrict__ fcb,
    float* __restrict__ Cg)
{
    __shared__ float hid[2][4][4];
    const int t = threadIdx.x;
    if (t < 32) {
        int which = t >> 4, b = (t >> 2) & 3, h = t & 3;
        const float* src = which ? av : mx;
        float s = 0.f;
        for (int i = 0; i < C; ++i) s += caw1[h * C + i] * src[b * C + i];
        hid[which][b][h] = fmaxf(s, 0.f);
    }
    __syncthreads();
    int b = t >> 6, c = t & 63;
    float s = 0.f;
#pragma unroll
    for (int h = 0; h < 4; ++h)
        s += caw2[c * 4 + h] * (hid[0][b][h] + hid[1][b][h]);
    float xll = 1.f / (1.f + expf(-s));
    Cg[t] = fcw[1] * (fcw[0] * xll + fcb[0]) + fcb[1];
}

// out(fp32 NCHW) = o(fp16 NHWC) * map + x, LDS transpose
__global__ __launch_bounds__(256) void final_kernel(
    const _Float16* __restrict__ o, const float* __restrict__ mapp,
    const float* __restrict__ x, float* __restrict__ out)
{
    __shared__ _Float16 s[64 * 72];
    const int b = blockIdx.y;
    const size_t p0 = (size_t)blockIdx.x * 64;
    const int t = threadIdx.x;
#pragma unroll
    for (int k = 0; k < 2; ++k) {
        int idx = k * 256 + t;
        int pxw = idx >> 3, o8 = idx & 7;
        uint4 v = *(const uint4*)&o[((size_t)b * HW + p0 + pxw) * 64 + o8 * 8];
        *(uint4*)&s[pxw * 72 + o8 * 8] = v;
    }
    __syncthreads();
    const int px = t & 63, cg0 = t >> 6;
    const float mv = mapp[(size_t)b * HW + p0 + px];
#pragma unroll
    for (int k = 0; k < 16; ++k) {
        int c = cg0 * 16 + k;
        size_t off = ((size_t)(b * 64 + c)) * HW + p0 + px;
        out[off] = (float)s[px * 72 + c] * mv + x[off];
    }
}

extern "C" void kernel_launch(void* const* d_in, const int* in_sizes, int n_in,
                              void* d_out, int out_size, void* d_ws, size_t ws_size,
                              hipStream_t stream)
{
    const float* x    = (const float*)d_in[0];
    const float* cf1  = (const float*)d_in[1];
    const float* cf2  = (const float*)d_in[2];
    const float* mapp = (const float*)d_in[3];
    const float* rw   = (const float*)d_in[4];
    const float* rb   = (const float*)d_in[5];
    const float* mw1  = (const float*)d_in[6];
    const float* mb1  = (const float*)d_in[7];
    const float* mw3  = (const float*)d_in[8];
    const float* mb3  = (const float*)d_in[9];
    const float* mw5  = (const float*)d_in[10];
    const float* mb5  = (const float*)d_in[11];
    const float* caw1 = (const float*)d_in[12];
    const float* caw2 = (const float*)d_in[13];
    const float* fcw  = (const float*)d_in[14];
    const float* fcb  = (const float*)d_in[15];
    float* out = (float*)d_out;

    _Float16* wta = (_Float16*)d_ws;
    _Float16* hb  = wta + A_TOT;
    _Float16* xh  = hb;
    _Float16* o   = hb + TOT;
    _Float16* t   = hb + 2 * TOT;
    _Float16* ac  = hb + 3 * TOT;
    float* st = (float*)(hb + 4 * TOT);
    float* mxp = st, *avp = st + 256, *Cg = st + 512;

    wt_kernel<<<dim3((unsigned)(A_TOT / 256)), 256, 0, stream>>>(rw, mw1, mw3, mw5, cf1, cf2, wta);
    xcvt_kernel<<<dim3(256, B), 256, 0, stream>>>(x, xh);

    const dim3 cgrid(128, B);

    int mfe_j = 0;
    for (int i = 0; i < 9; ++i) {
        const _Float16* in0 = (i == 0) ? xh : o;
        // r = relu(conv(o, W0*SCALE*cond0) + rb0)
        mconv_kernel<3, 1><<<cgrid, 256, 0, stream>>>(
            in0, wta + A_RES + (size_t)(i * 2 + 0) * 4 * 36864, rb + (i * 2 + 0) * C,
            36864, nullptr, nullptr, t);
        // o = conv(r, W1*SCALE*cond1) + rb1 + o
        mconv_kernel<3, 0><<<cgrid, 256, 0, stream>>>(
            t, wta + A_RES + (size_t)(i * 2 + 1) * 4 * 36864, rb + (i * 2 + 1) * C,
            36864, in0, nullptr, o);

        if (i == 1 || i == 3 || i == 5 || i == 7 || i == 8) {
            int j = mfe_j++;
            pool_kernel<<<dim3(32), 256, 0, stream>>>(o, mxp, avp);
            cg_kernel<<<1, 256, 0, stream>>>(mxp, avp, caw1 + j * 4 * C, caw2 + j * C * 4,
                                             fcw + j * 2, fcb + j * 2, Cg);
            // x1: ac = Cg*(conv(lrelu(conv(o))) + b)
            mconv_kernel<1, 2><<<cgrid, 256, 0, stream>>>(
                o, wta + A_M1 + (size_t)(j * 2 + 0) * 4096, mb1 + (j * 2 + 0) * C,
                0, nullptr, nullptr, t);
            mconv_kernel<1, 0><<<cgrid, 256, 0, stream>>>(
                t, wta + A_M1 + (size_t)(j * 2 + 1) * 4096, mb1 + (j * 2 + 1) * C,
                0, nullptr, Cg, ac);
            // x3: ac += Cg*(...)
            mconv_kernel<3, 2><<<cgrid, 256, 0, stream>>>(
                o, wta + A_M3 + (size_t)(j * 2 + 0) * 36864, mb3 + (j * 2 + 0) * C,
                0, nullptr, nullptr, t);
            mconv_kernel<3, 0><<<cgrid, 256, 0, stream>>>(
                t, wta + A_M3 + (size_t)(j * 2 + 1) * 36864, mb3 + (j * 2 + 1) * C,
                0, ac, Cg, ac);
            // x5: o = ac + Cg*(...)
            mconv_kernel<5, 2><<<cgrid, 256, 0, stream>>>(
                o, wta + A_M5 + (size_t)(j * 2 + 0) * 102400, mb5 + (j * 2 + 0) * C,
                0, nullptr, nullptr, t);
            mconv_kernel<5, 0><<<cgrid, 256, 0, stream>>>(
                t, wta + A_M5 + (size_t)(j * 2 + 1) * 102400, mb5 + (j * 2 + 1) * C,
                0, ac, Cg, o);
        }
    }
    final_kernel<<<dim3(256, B), 256, 0, stream>>>(o, mapp, x, out);
}